// Round 14
// baseline (71.284 us; speedup 1.0000x reference)
//
#include <hip/hip_runtime.h>
#include <hip/hip_bf16.h>

// ConvexWidthUpsampler R14: R13 + 1-tile software pipeline.
// Softmax+store of tile t-1 (pure VALU/trans, from carried registers) is
// placed INSIDE tile t's MFMA+scatter scheduling region so the scheduler
// fills MFMA dependency stalls with exp2/fma work.
// All LDS staging, fences, 112B self-swizzling rows: identical to R13.
// z stays in registers (permuted-M2 trick, R11-proven).
// B=16,C=1,H=512,W=512,up=(1,3). Output [16,1,512,1536] f32 (ob = p*3).

#define BB 16
#define HH 512
#define WW 512
#define HID 32
#define NM 27
#define LOG2E 1.44269504088896340736f
#define NT 16384
#define NBLK 1280
#define ROWB 112
#define ZOFF (64 * ROWB)   // 7168: per-wave broadcast-zero block

typedef short bf16x8 __attribute__((ext_vector_type(8)));
typedef float f32x4  __attribute__((ext_vector_type(4)));
typedef unsigned int u32;
typedef u32 u32x4 __attribute__((ext_vector_type(4)));

__device__ __forceinline__ u32 pk2(float a, float b) {
    union { __hip_bfloat162 h2; u32 u; } cv;
    cv.h2 = __float22bfloat162_rn(make_float2(a, b));
    return cv.u;
}

// Compiler memory fence (free at runtime): blocks CSE/TBAA reordering of LDS
// ops across stages; a wave's DS instructions execute in issue order in HW.
__device__ __forceinline__ void lds_fence() {
    asm volatile("" ::: "memory");
    __builtin_amdgcn_sched_barrier(0);
}

// Clamped-address 3x3 load: addresses always in-bounds, zeros via cndmask.
__device__ __forceinline__ void load_xv(const float* __restrict__ x, int tile,
                                        int tid, float xv[9]) {
    const int p    = tile * 256 + tid;
    const int wcol = p & (WW - 1);
    const int t    = p >> 9;
    const int hrow = t & (HH - 1);
    const int bidx = t >> 9;
    const float* xb = x + (size_t)bidx * (HH * WW);
    int hy[3], wx[3];
    bool hok[3], wok[3];
#pragma unroll
    for (int i = 0; i < 3; ++i) {
        const int h = hrow + i - 1;
        hok[i] = (unsigned)h < (unsigned)HH;
        hy[i]  = h < 0 ? 0 : (h > HH - 1 ? HH - 1 : h);
        const int w = wcol + i - 1;
        wok[i] = (unsigned)w < (unsigned)WW;
        wx[i]  = w < 0 ? 0 : (w > WW - 1 ? WW - 1 : w);
    }
#pragma unroll
    for (int ki = 0; ki < 3; ++ki)
#pragma unroll
        for (int kj = 0; kj < 3; ++kj) {
            const float v = xb[hy[ki] * WW + wx[kj]];
            xv[ki * 3 + kj] = (hok[ki] && wok[kj]) ? v : 0.0f;
        }
}

// Softmax (base-2, pre-scaled logits) + convex combine + store, all from
// carried registers. x comes from the packed-bf16 init words (pxp).
__device__ __forceinline__ void softmax_store(const f32x4 mv[7], const u32 pxp[5],
                                              int p, float* __restrict__ out) {
    float xq[9];
#pragma unroll
    for (int i = 0; i < 4; ++i) {
        xq[2 * i]     = __uint_as_float(pxp[i] << 16);
        xq[2 * i + 1] = __uint_as_float(pxp[i] & 0xffff0000u);
    }
    xq[8] = __uint_as_float(pxp[4] << 16);
    const size_t ob = (size_t)p * 3;
#pragma unroll
    for (int v = 0; v < 3; ++v) {
        float ssum = 0.0f, acc = 0.0f;
#pragma unroll
        for (int k = 0; k < 9; ++k) {
            const int j = k * 3 + v;
            const float lg = (j < 16) ? mv[j >> 2][j & 3]
                                      : mv[4 + ((j - 16) >> 2)][(j - 16) & 3];
            const float e = __builtin_amdgcn_exp2f(lg);
            ssum += e;
            acc = fmaf(xq[k], e, acc);
        }
        out[ob + v] = acc * __builtin_amdgcn_rcpf(ssum);
    }
}

// ws bf16 layout (hi-only, 3072 elems = 6 KB):
//   [0   ..1023] B2_32 [32 n][32 k]: k<9 M1[n][k], k==9 bias'[n], else 0 (xlog2e)
//   [1024..2047] M2p   [32 n][32 k]: M2[n][pi(k)] (xlog2e), n>=27 -> 0
//   [2048..3071] B1    [32 n][32 k]: k<9 w1[n][k], k==9 b1[n], else 0
__global__ void prep_B(const float* __restrict__ w1, const float* __restrict__ b1,
                       const float* __restrict__ alpha, const float* __restrict__ w2,
                       const float* __restrict__ b2, __hip_bfloat16* __restrict__ ws) {
    const int i = blockIdx.x * 256 + threadIdx.x;
    if (i >= 3072) return;
    const int sec = i >> 10;
    const int r   = i & 1023;
    const int n   = r >> 5, k = r & 31;
    float v = 0.0f;
    if (sec == 0) {
        if (n < NM) {
            if (k < 9) {
                for (int c = 0; c < HID; ++c)
                    v += w2[n * HID + c] * (0.5f * (1.0f + alpha[c])) * w1[c * 9 + k];
            } else if (k == 9) {
                v = b2[n];
                for (int c = 0; c < HID; ++c)
                    v += w2[n * HID + c] * (0.5f * (1.0f + alpha[c])) * b1[c];
            }
        }
        v *= LOG2E;
    } else if (sec == 1) {
        if (n < NM) {
            const int c = ((k & 4) ? 16 : 0) + (k >> 3) * 4 + (k & 3);  // pi(k)
            v = w2[n * HID + c] * (0.5f * (1.0f - alpha[c])) * LOG2E;
        }
    } else {
        v = (k < 9) ? w1[n * 9 + k] : (k == 9 ? b1[n] : 0.0f);
    }
    ws[i] = __float2bfloat16(v);
}

__global__ __launch_bounds__(256, 4) void convex_upsample_mfma10(
    const float* __restrict__ x,            // [16,1,512,512]
    const __hip_bfloat16* __restrict__ ws,  // prep output
    float* __restrict__ out)                // [16,1,512,1536]
{
    __shared__ char lds_raw[4][ZOFF + 16];  // 4 x 7184 = 28736 B -> 5 blocks/CU

    const int tid  = threadIdx.x;
    const int wv   = tid >> 6;
    const int lane = tid & 63;
    const int l16  = lane & 15;
    const int lq   = lane >> 4;
    char* wbase = lds_raw[wv];

    // persistent weight fragments (hi only): lane row n = nt*16+l16, k = lq*8+i
    bf16x8 Bf2[2], M2p[2], Bf1[2];
#pragma unroll
    for (int nt = 0; nt < 2; ++nt) {
        const int ro = (nt * 16 + l16) * 32 + lq * 8;
        Bf2[nt] = *(const bf16x8*)(ws + ro);
        M2p[nt] = *(const bf16x8*)(ws + 1024 + ro);
        Bf1[nt] = *(const bf16x8*)(ws + 2048 + ro);
    }

    // broadcast-zero block (idempotent per-wave write; read by lq>=2 a0 loads)
    *(u32x4*)(wbase + ZOFF) = (u32x4){0u, 0u, 0u, 0u};

    int tb = blockIdx.x;
    float xv[9];
    load_xv(x, tb, tid, xv);
    u32 px[5] = {pk2(xv[0], xv[1]), pk2(xv[2], xv[3]), pk2(xv[4], xv[5]),
                 pk2(xv[6], xv[7]), pk2(xv[8], 1.0f)};

    // "previous tile" state; dummy first round writes zeros to out[pp*3..]
    // which this same thread later overwrites with the real values.
    f32x4 mv[7];
#pragma unroll
    for (int q = 0; q < 7; ++q) mv[q] = (f32x4){0.f, 0.f, 0.f, 0.f};
    u32 pxp[5] = {0u, 0u, 0u, 0u, 0u};
    int pp = tb * 256 + tid;

    while (tb < NT) {
        const int tn  = tb + NBLK;
        const int tpf = (tn < NT) ? tn : 0;
        float xn[9];
        load_xv(x, tpf, tid, xn);   // prefetch next tile during this compute

        // ---- init my row bytes 0..31: k0..8=xv, k9=1, k10..15=0 ----
        char* myrow = wbase + lane * ROWB;
        *(u32x4*)(myrow)      = (u32x4){px[0], px[1], px[2], px[3]};
        *(u32x4*)(myrow + 16) = (u32x4){px[4], 0u, 0u, 0u};

        lds_fence();   // init writes -> cross-lane a0 reads

        // ---- hoisted a0 reads; lq>=2 lanes read the broadcast-zero block ----
        bf16x8 a0[4];
#pragma unroll
        for (int mt = 0; mt < 4; ++mt) {
            const char* ab = wbase + (mt * 16 + l16) * ROWB;
            const char* aptr = (lq < 2) ? (ab + lq * 16) : (wbase + ZOFF);
            a0[mt] = *(const bf16x8*)aptr;
        }

        lds_fence();   // a0 reads -> scatters below (TBAA/reorder guard)

        // ---- softmax+store of PREVIOUS tile: same scheduling region as the
        //      MFMA chain below -> scheduler fills MFMA stalls with VALU/trans.
        softmax_store(mv, pxp, pp, out);

        // ---- per mt: z in-register -> logits -> scatter ----
#pragma unroll
        for (int mt = 0; mt < 4; ++mt) {
            char* ab = wbase + (mt * 16 + l16) * ROWB;
            // round 1: z[ch][px]; lane(l16,lq) gets ch = {lq*4+r, 16+lq*4+r}, px = l16
            f32x4 z0 = {0.f, 0.f, 0.f, 0.f}, z1 = {0.f, 0.f, 0.f, 0.f};
            z0 = __builtin_amdgcn_mfma_f32_16x16x32_bf16(Bf1[0], a0[mt], z0, 0, 0, 0);
            z1 = __builtin_amdgcn_mfma_f32_16x16x32_bf16(Bf1[1], a0[mt], z1, 0, 0, 0);
            // pack |z| as permuted B-operand fragment (k = lq*8+i -> ch pi(k))
            union { u32 u[4]; bf16x8 h; } zf;
            zf.u[0] = pk2(fabsf(z0[0]), fabsf(z0[1]));
            zf.u[1] = pk2(fabsf(z0[2]), fabsf(z0[3]));
            zf.u[2] = pk2(fabsf(z1[0]), fabsf(z1[1]));
            zf.u[3] = pk2(fabsf(z1[2]), fabsf(z1[3]));
            // round 2: logits m[n][px] = M2p*|z| + B2*a0
            f32x4 c0 = {0.f, 0.f, 0.f, 0.f}, c1 = {0.f, 0.f, 0.f, 0.f};
            c0 = __builtin_amdgcn_mfma_f32_16x16x32_bf16(M2p[0], zf.h,   c0, 0, 0, 0);
            c0 = __builtin_amdgcn_mfma_f32_16x16x32_bf16(Bf2[0], a0[mt], c0, 0, 0, 0);
            c1 = __builtin_amdgcn_mfma_f32_16x16x32_bf16(M2p[1], zf.h,   c1, 0, 0, 0);
            c1 = __builtin_amdgcn_mfma_f32_16x16x32_bf16(Bf2[1], a0[mt], c1, 0, 0, 0);
            // scatter for pixel mt*16+l16: lane(l16,lq) holds
            //   c0: n = lq*4..+3      -> bytes 48 + lq*16 (48..111)
            //   c1: n = 16+lq*4..+3   -> bytes lq*16 (0..47), lq==3 (n>=28) dropped
            *(f32x4*)(ab + 48 + lq * 16) = c0;
            if (lq < 3) *(f32x4*)(ab + lq * 16) = c1;
        }

        lds_fence();   // scatters -> readback

        // ---- readback 27 logits into mv: n0..15 @ 48..111, n16..26 @ 0..43 ----
#pragma unroll
        for (int q = 0; q < 4; ++q)
            mv[q] = *(const f32x4*)(myrow + 48 + q * 16);
#pragma unroll
        for (int q = 0; q < 3; ++q)
            mv[4 + q] = *(const f32x4*)(myrow + q * 16);

        // ---- rotate pipeline state ----
#pragma unroll
        for (int i = 0; i < 5; ++i) pxp[i] = px[i];
        pp = tb * 256 + tid;
        px[0] = pk2(xn[0], xn[1]); px[1] = pk2(xn[2], xn[3]);
        px[2] = pk2(xn[4], xn[5]); px[3] = pk2(xn[6], xn[7]);
        px[4] = pk2(xn[8], 1.0f);

        lds_fence();   // readback -> next iteration's init writes

        tb = tn;
    }

    // epilogue: finish the last tile
    softmax_store(mv, pxp, pp, out);
}

extern "C" void kernel_launch(void* const* d_in, const int* in_sizes, int n_in,
                              void* d_out, int out_size, void* d_ws, size_t ws_size,
                              hipStream_t stream) {
    // setup_inputs order: x, target_h, target_w, w1, b1, alpha, w2, b2
    const float* x     = (const float*)d_in[0];
    const float* w1    = (const float*)d_in[3];
    const float* b1    = (const float*)d_in[4];
    const float* alpha = (const float*)d_in[5];
    const float* w2    = (const float*)d_in[6];
    const float* b2    = (const float*)d_in[7];
    float* out = (float*)d_out;
    __hip_bfloat16* ws = (__hip_bfloat16*)d_ws;   // 3072 bf16 = 6 KB

    hipLaunchKernelGGL(prep_B, dim3(12), dim3(256), 0, stream, w1, b1, alpha, w2, b2, ws);
    hipLaunchKernelGGL(convex_upsample_mfma10, dim3(NBLK), dim3(256), 0, stream,
                       x, ws, out);
}

// Round 15
// 58.045 us; speedup vs baseline: 1.2281x; 1.2281x over previous
//
#include <hip/hip_runtime.h>
#include <hip/hip_bf16.h>

// ConvexWidthUpsampler R15: R13 structure with (1) fences weakened to a pure
// compiler memory clobber (no sched_barrier -> scheduler interleaves softmax
// VALU with MFMA/DS stalls), (2) scalar (wave-uniform) row addressing,
// (3) ob = 3p store addressing. 112B self-swizzling rows, 5 blocks/CU.
// z stays in registers (permuted-M2 trick, R11-proven).
// B=16,C=1,H=512,W=512,up=(1,3). Output [16,1,512,1536] f32.

#define BB 16
#define HH 512
#define WW 512
#define HID 32
#define NM 27
#define LOG2E 1.44269504088896340736f
#define NT 16384
#define NBLK 1280
#define ROWB 112
#define ZOFF (64 * ROWB)   // 7168: per-wave broadcast-zero block

typedef short bf16x8 __attribute__((ext_vector_type(8)));
typedef float f32x4  __attribute__((ext_vector_type(4)));
typedef unsigned int u32;
typedef u32 u32x4 __attribute__((ext_vector_type(4)));

__device__ __forceinline__ u32 pk2(float a, float b) {
    union { __hip_bfloat162 h2; u32 u; } cv;
    cv.h2 = __float22bfloat162_rn(make_float2(a, b));
    return cv.u;
}

// Compiler memory fence: forbids CSE/reordering of LDS ops across stages
// (TBAA guard for type-punned same-address accesses, the R5 bug class).
// NO sched_barrier: non-memory VALU/MFMA may float across for latency hiding.
// HW executes a wave's DS instructions in issue order, so compiler-level
// ordering is sufficient.
__device__ __forceinline__ void lds_fence() {
    asm volatile("" ::: "memory");
}

// 3x3 load with wave-uniform row logic: block covers half of one image row,
// so hrow/bidx/row-masks are scalar (derived from tile index only).
__device__ __forceinline__ void load_xv(const float* __restrict__ x, int tile,
                                        int tid, float xv[9]) {
    const int wcol = (tile & 1) * 256 + tid;       // lane-varying
    const int hrow = (tile >> 1) & (HH - 1);       // scalar
    const int bidx = tile >> 10;                   // scalar
    const float* xb = x + (size_t)bidx * (HH * WW);
    int wx[3]; bool wok[3];
#pragma unroll
    for (int i = 0; i < 3; ++i) {
        const int w = wcol + i - 1;
        wok[i] = (unsigned)w < (unsigned)WW;
        wx[i]  = w < 0 ? 0 : (w > WW - 1 ? WW - 1 : w);
    }
#pragma unroll
    for (int ki = 0; ki < 3; ++ki) {
        const int h = hrow + ki - 1;                       // scalar
        const bool hok = (unsigned)h < (unsigned)HH;       // scalar
        const int hy = h < 0 ? 0 : (h > HH - 1 ? HH - 1 : h);
        const float* rowp = xb + hy * WW;                  // scalar base
#pragma unroll
        for (int kj = 0; kj < 3; ++kj) {
            const float v = rowp[wx[kj]];
            xv[ki * 3 + kj] = (hok && wok[kj]) ? v : 0.0f;
        }
    }
}

// ws bf16 layout (hi-only, 3072 elems = 6 KB):
//   [0   ..1023] B2_32 [32 n][32 k]: k<9 M1[n][k], k==9 bias'[n], else 0 (xlog2e)
//   [1024..2047] M2p   [32 n][32 k]: M2[n][pi(k)] (xlog2e), n>=27 -> 0
//   [2048..3071] B1    [32 n][32 k]: k<9 w1[n][k], k==9 b1[n], else 0
__global__ void prep_B(const float* __restrict__ w1, const float* __restrict__ b1,
                       const float* __restrict__ alpha, const float* __restrict__ w2,
                       const float* __restrict__ b2, __hip_bfloat16* __restrict__ ws) {
    const int i = blockIdx.x * 256 + threadIdx.x;
    if (i >= 3072) return;
    const int sec = i >> 10;
    const int r   = i & 1023;
    const int n   = r >> 5, k = r & 31;
    float v = 0.0f;
    if (sec == 0) {
        if (n < NM) {
            if (k < 9) {
                for (int c = 0; c < HID; ++c)
                    v += w2[n * HID + c] * (0.5f * (1.0f + alpha[c])) * w1[c * 9 + k];
            } else if (k == 9) {
                v = b2[n];
                for (int c = 0; c < HID; ++c)
                    v += w2[n * HID + c] * (0.5f * (1.0f + alpha[c])) * b1[c];
            }
        }
        v *= LOG2E;
    } else if (sec == 1) {
        if (n < NM) {
            const int c = ((k & 4) ? 16 : 0) + (k >> 3) * 4 + (k & 3);  // pi(k)
            v = w2[n * HID + c] * (0.5f * (1.0f - alpha[c])) * LOG2E;
        }
    } else {
        v = (k < 9) ? w1[n * 9 + k] : (k == 9 ? b1[n] : 0.0f);
    }
    ws[i] = __float2bfloat16(v);
}

__global__ __launch_bounds__(256, 5) void convex_upsample_mfma11(
    const float* __restrict__ x,            // [16,1,512,512]
    const __hip_bfloat16* __restrict__ ws,  // prep output
    float* __restrict__ out)                // [16,1,512,1536]
{
    __shared__ char lds_raw[4][ZOFF + 16];  // 4 x 7184 = 28736 B -> 5 blocks/CU

    const int tid  = threadIdx.x;
    const int wv   = tid >> 6;
    const int lane = tid & 63;
    const int l16  = lane & 15;
    const int lq   = lane >> 4;
    char* wbase = lds_raw[wv];

    // persistent weight fragments (hi only): lane row n = nt*16+l16, k = lq*8+i
    bf16x8 Bf2[2], M2p[2], Bf1[2];
#pragma unroll
    for (int nt = 0; nt < 2; ++nt) {
        const int ro = (nt * 16 + l16) * 32 + lq * 8;
        Bf2[nt] = *(const bf16x8*)(ws + ro);
        M2p[nt] = *(const bf16x8*)(ws + 1024 + ro);
        Bf1[nt] = *(const bf16x8*)(ws + 2048 + ro);
    }

    // broadcast-zero block (idempotent per-wave write; read by lq>=2 a0 loads)
    *(u32x4*)(wbase + ZOFF) = (u32x4){0u, 0u, 0u, 0u};

    int tb = blockIdx.x;
    float xv[9];
    load_xv(x, tb, tid, xv);

    while (tb < NT) {
        const int tn  = tb + NBLK;
        const int tpf = (tn < NT) ? tn : 0;
        float xn[9];
        load_xv(x, tpf, tid, xn);   // prefetch next tile during this compute

        // ---- init my row bytes 0..31: k0..8=xv, k9=1, k10..15=0 ----
        char* myrow = wbase + lane * ROWB;
        *(u32x4*)(myrow)      = (u32x4){pk2(xv[0], xv[1]), pk2(xv[2], xv[3]),
                                        pk2(xv[4], xv[5]), pk2(xv[6], xv[7])};
        *(u32x4*)(myrow + 16) = (u32x4){pk2(xv[8], 1.0f), 0u, 0u, 0u};

        lds_fence();   // init writes -> cross-lane a0 reads

        // ---- hoisted a0 reads; lq>=2 lanes read the broadcast-zero block ----
        bf16x8 a0[4];
#pragma unroll
        for (int mt = 0; mt < 4; ++mt) {
            const char* ab = wbase + (mt * 16 + l16) * ROWB;
            const char* aptr = (lq < 2) ? (ab + lq * 16) : (wbase + ZOFF);
            a0[mt] = *(const bf16x8*)aptr;
        }

        lds_fence();   // a0 reads -> scatters below (TBAA/reorder guard)

        // ---- per mt: z in-register -> logits -> scatter ----
#pragma unroll
        for (int mt = 0; mt < 4; ++mt) {
            char* ab = wbase + (mt * 16 + l16) * ROWB;
            // round 1: z[ch][px]; lane(l16,lq) gets ch = {lq*4+r, 16+lq*4+r}, px = l16
            f32x4 z0 = {0.f, 0.f, 0.f, 0.f}, z1 = {0.f, 0.f, 0.f, 0.f};
            z0 = __builtin_amdgcn_mfma_f32_16x16x32_bf16(Bf1[0], a0[mt], z0, 0, 0, 0);
            z1 = __builtin_amdgcn_mfma_f32_16x16x32_bf16(Bf1[1], a0[mt], z1, 0, 0, 0);
            // pack |z| as permuted B-operand fragment (k = lq*8+i -> ch pi(k))
            union { u32 u[4]; bf16x8 h; } zf;
            zf.u[0] = pk2(fabsf(z0[0]), fabsf(z0[1]));
            zf.u[1] = pk2(fabsf(z0[2]), fabsf(z0[3]));
            zf.u[2] = pk2(fabsf(z1[0]), fabsf(z1[1]));
            zf.u[3] = pk2(fabsf(z1[2]), fabsf(z1[3]));
            // round 2: logits m[n][px] = M2p*|z| + B2*a0
            f32x4 c0 = {0.f, 0.f, 0.f, 0.f}, c1 = {0.f, 0.f, 0.f, 0.f};
            c0 = __builtin_amdgcn_mfma_f32_16x16x32_bf16(M2p[0], zf.h,   c0, 0, 0, 0);
            c0 = __builtin_amdgcn_mfma_f32_16x16x32_bf16(Bf2[0], a0[mt], c0, 0, 0, 0);
            c1 = __builtin_amdgcn_mfma_f32_16x16x32_bf16(M2p[1], zf.h,   c1, 0, 0, 0);
            c1 = __builtin_amdgcn_mfma_f32_16x16x32_bf16(Bf2[1], a0[mt], c1, 0, 0, 0);
            // scatter for pixel mt*16+l16: lane(l16,lq) holds
            //   c0: n = lq*4..+3      -> bytes 48 + lq*16 (48..111)
            //   c1: n = 16+lq*4..+3   -> bytes lq*16 (0..47), lq==3 (n>=28) dropped
            *(f32x4*)(ab + 48 + lq * 16) = c0;
            if (lq < 3) *(f32x4*)(ab + lq * 16) = c1;
        }

        lds_fence();   // scatters -> readback

        // ---- readback 27 logits: n0..15 @ bytes 48..111, n16..26 @ 0..43 ----
        f32x4 mv[7];
#pragma unroll
        for (int q = 0; q < 4; ++q)
            mv[q] = *(const f32x4*)(myrow + 48 + q * 16);
#pragma unroll
        for (int q = 0; q < 3; ++q)
            mv[4 + q] = *(const f32x4*)(myrow + q * 16);

        // ---- softmax (base-2, pre-scaled, no max-sub) + combine + store ----
        const int p = tb * 256 + tid;
        const size_t ob = (size_t)p * 3;
#pragma unroll
        for (int v = 0; v < 3; ++v) {
            float ssum = 0.0f, acc = 0.0f;
#pragma unroll
            for (int k = 0; k < 9; ++k) {
                const int j = k * 3 + v;
                const float lg = (j < 16) ? mv[j >> 2][j & 3]
                                          : mv[4 + ((j - 16) >> 2)][(j - 16) & 3];
                const float e = __builtin_amdgcn_exp2f(lg);
                ssum += e;
                acc = fmaf(xv[k], e, acc);
            }
            out[ob + v] = acc * __builtin_amdgcn_rcpf(ssum);
        }

        lds_fence();   // readback -> next iteration's init writes

        tb = tn;
#pragma unroll
        for (int k = 0; k < 9; ++k) xv[k] = xn[k];
    }
}

extern "C" void kernel_launch(void* const* d_in, const int* in_sizes, int n_in,
                              void* d_out, int out_size, void* d_ws, size_t ws_size,
                              hipStream_t stream) {
    // setup_inputs order: x, target_h, target_w, w1, b1, alpha, w2, b2
    const float* x     = (const float*)d_in[0];
    const float* w1    = (const float*)d_in[3];
    const float* b1    = (const float*)d_in[4];
    const float* alpha = (const float*)d_in[5];
    const float* w2    = (const float*)d_in[6];
    const float* b2    = (const float*)d_in[7];
    float* out = (float*)d_out;
    __hip_bfloat16* ws = (__hip_bfloat16*)d_ws;   // 3072 bf16 = 6 KB

    hipLaunchKernelGGL(prep_B, dim3(12), dim3(256), 0, stream, w1, b1, alpha, w2, b2, ws);
    hipLaunchKernelGGL(convex_upsample_mfma11, dim3(NBLK), dim3(256), 0, stream,
                       x, ws, out);
}